// Round 1
// baseline (13145.786 us; speedup 1.0000x reference)
//
#include <hip/hip_runtime.h>
#include <math.h>

// Problem constants
#define EDIM 300
#define HDIM 512
#define TDIM 100
#define BDIM 256
#define KTOT 812      // E + H
#define FOURH 2048
#define ENC 1024

// Workspace layout (in floats)
// c:    [2][256][512]            @ 0        (262144)
// h:    [2 parity][2][256][512]  @ 262144   (524288)
// ctx:  [256][1024]              @ 786432   (262144)
// x1:   [256][1024]              @ 1048576  (262144)
// x2:   [256][1024]              @ 1310720  (262144)
#define OFF_C   0
#define OFF_H   262144
#define OFF_CTX 786432
#define OFF_X1  1048576
#define OFF_X2  1310720

__device__ __forceinline__ float fast_sigmoid(float x) {
    // 1/(1+e^-x); e^-x -> inf for very negative x gives 0, -> 0 for large x gives 1. Safe.
    return 1.0f / (1.0f + __expf(-x));
}
__device__ __forceinline__ float fast_tanh(float x) {
    // 1 - 2/(e^{2x}+1); e^{2x}=inf -> 1, e^{2x}=0 -> -1. NaN-free saturation.
    float t = __expf(2.0f * x);
    return 1.0f - 2.0f / (t + 1.0f);
}

__global__ void zero_kernel(float* __restrict__ p, int n) {
    int i = blockIdx.x * blockDim.x + threadIdx.x;
    if (i < n) p[i] = 0.0f;
}

// One LSTM timestep for both directions.
// Block tile: 32 batch rows x 32 h-columns, computed for all 4 gates (128 z cols).
// grid = (512/32, 256/32, 2) = (16, 8, 2), 256 threads.
__global__ __launch_bounds__(256) void lstm_step(
    const float* __restrict__ xL, const float* __restrict__ xR,
    const int* __restrict__ lenL, const int* __restrict__ lenR,
    const float* __restrict__ WL, const float* __restrict__ WR,
    const float* __restrict__ bLp, const float* __restrict__ bRp,
    float* __restrict__ ws, int t, int par)
{
    const int d = blockIdx.z;
    const float* __restrict__ x    = d ? xR   : xL;
    const int*   __restrict__ len  = d ? lenR : lenL;
    const float* __restrict__ W    = d ? WR   : WL;
    const float* __restrict__ bias = d ? bRp  : bLp;

    float* __restrict__ cbuf  = ws + OFF_C;
    float* __restrict__ hprev = ws + OFF_H + (size_t)par       * 262144;
    float* __restrict__ hnext = ws + OFF_H + (size_t)(par ^ 1) * 262144;
    float* __restrict__ ctx   = ws + OFF_CTX;

    const int n0 = blockIdx.x * 32;   // h-column tile base
    const int b0 = blockIdx.y * 32;   // batch tile base

    // As[kk][m] (transposed for vectorized compute reads), stride 36 to dodge conflicts
    __shared__ __align__(16) float As[32 * 36];
    // Bs[kk][g*32 + j], stride 132
    __shared__ __align__(16) float Bs[32 * 132];

    const int tid = threadIdx.x;
    const int j   = tid & 31;        // h-column within tile (also k-offset for A staging)
    const int mg  = tid >> 5;        // 0..7
    const int m0t = mg * 4;          // 4 consecutive batch rows per thread

    float acc[4][4];                 // [m][gate]
    #pragma unroll
    for (int a = 0; a < 4; ++a)
        #pragma unroll
        for (int g = 0; g < 4; ++g) acc[a][g] = 0.0f;

    for (int k0 = 0; k0 < KTOT; k0 += 32) {
        // ---- stage A tile: [32 m][32 k], sources: x_t (k<300) then h_prev (k>=300)
        {
            int kg = k0 + j;
            #pragma unroll
            for (int pass = 0; pass < 4; ++pass) {
                int m = mg + pass * 8;
                float v = 0.0f;
                if (kg < EDIM) {
                    v = x[(size_t)(b0 + m) * (TDIM * EDIM) + (size_t)t * EDIM + kg];
                } else if (kg < KTOT) {
                    v = hprev[(size_t)(d * BDIM + b0 + m) * HDIM + (kg - EDIM)];
                }
                As[j * 36 + m] = v;
            }
        }
        // ---- stage B tile: W[k][g*512 + n0 + j] for 4 gates
        #pragma unroll
        for (int g = 0; g < 4; ++g) {
            #pragma unroll
            for (int pass = 0; pass < 4; ++pass) {
                int kk = mg + pass * 8;
                int kg = k0 + kk;
                float v = 0.0f;
                if (kg < KTOT) v = W[(size_t)kg * FOURH + g * HDIM + n0 + j];
                Bs[kk * 132 + g * 32 + j] = v;
            }
        }
        __syncthreads();
        // ---- compute: 16 FMAs per k
        #pragma unroll
        for (int kk = 0; kk < 32; ++kk) {
            float4 a4 = *(const float4*)&As[kk * 36 + m0t];
            float bv0 = Bs[kk * 132 + 0 * 32 + j];
            float bv1 = Bs[kk * 132 + 1 * 32 + j];
            float bv2 = Bs[kk * 132 + 2 * 32 + j];
            float bv3 = Bs[kk * 132 + 3 * 32 + j];
            acc[0][0] += a4.x * bv0; acc[0][1] += a4.x * bv1; acc[0][2] += a4.x * bv2; acc[0][3] += a4.x * bv3;
            acc[1][0] += a4.y * bv0; acc[1][1] += a4.y * bv1; acc[1][2] += a4.y * bv2; acc[1][3] += a4.y * bv3;
            acc[2][0] += a4.z * bv0; acc[2][1] += a4.z * bv1; acc[2][2] += a4.z * bv2; acc[2][3] += a4.z * bv3;
            acc[3][0] += a4.w * bv0; acc[3][1] += a4.w * bv1; acc[3][2] += a4.w * bv2; acc[3][3] += a4.w * bv3;
        }
        __syncthreads();
    }

    // ---- epilogue: gates -> c,h update; record last output
    const int col = n0 + j;
    const float bi = bias[col];
    const float bj = bias[HDIM + col];
    const float bf = bias[2 * HDIM + col];
    const float bo = bias[3 * HDIM + col];
    #pragma unroll
    for (int mi = 0; mi < 4; ++mi) {
        int m = b0 + m0t + mi;
        size_t cidx = (size_t)(d * BDIM + m) * HDIM + col;
        float iv = acc[mi][0] + bi;
        float jv = acc[mi][1] + bj;
        float fv = acc[mi][2] + bf;
        float ov = acc[mi][3] + bo;
        float c_old = cbuf[cidx];
        float c_new = c_old * fast_sigmoid(fv + 1.0f) + fast_sigmoid(iv) * fast_tanh(jv);
        float h_new = fast_tanh(c_new) * fast_sigmoid(ov);
        cbuf[cidx]  = c_new;
        hnext[cidx] = h_new;
        if (t == len[m] - 1) {
            ctx[(size_t)m * (2 * HDIM) + d * HDIM + col] = h_new;
        }
    }
}

// C = relu(A @ W). A:[M,K], W:[K,N]. BM=32, BN=32, KC=32. grid (N/32, M/32), 256 thr.
__global__ __launch_bounds__(256) void gemm_relu(
    const float* __restrict__ A, const float* __restrict__ W, float* __restrict__ C,
    int M, int K, int N)
{
    __shared__ __align__(16) float As[32 * 36];
    __shared__ __align__(16) float Bs[32 * 36];
    const int tid = threadIdx.x;
    const int j   = tid & 31;
    const int mg  = tid >> 5;
    const int m0t = mg * 4;
    const int n0  = blockIdx.x * 32;
    const int b0  = blockIdx.y * 32;

    float acc[4] = {0.f, 0.f, 0.f, 0.f};
    for (int k0 = 0; k0 < K; k0 += 32) {
        #pragma unroll
        for (int pass = 0; pass < 4; ++pass) {
            int m  = mg + pass * 8;
            As[j * 36 + m] = A[(size_t)(b0 + m) * K + k0 + j];
            int kk = mg + pass * 8;
            Bs[kk * 36 + j] = W[(size_t)(k0 + kk) * N + n0 + j];
        }
        __syncthreads();
        #pragma unroll
        for (int kk = 0; kk < 32; ++kk) {
            float4 a4 = *(const float4*)&As[kk * 36 + m0t];
            float bv  = Bs[kk * 36 + j];
            acc[0] += a4.x * bv;
            acc[1] += a4.y * bv;
            acc[2] += a4.z * bv;
            acc[3] += a4.w * bv;
        }
        __syncthreads();
    }
    #pragma unroll
    for (int mi = 0; mi < 4; ++mi) {
        float v = acc[mi];
        v = v > 0.f ? v : 0.f;
        C[(size_t)(b0 + m0t + mi) * N + n0 + j] = v;
    }
}

extern "C" void kernel_launch(void* const* d_in, const int* in_sizes, int n_in,
                              void* d_out, int out_size, void* d_ws, size_t ws_size,
                              hipStream_t stream) {
    const float* xL   = (const float*)d_in[0];
    const int*   lenL = (const int*)  d_in[1];
    const float* xR   = (const float*)d_in[2];
    const int*   lenR = (const int*)  d_in[3];
    const float* WL   = (const float*)d_in[4];
    const float* bL   = (const float*)d_in[5];
    const float* WR   = (const float*)d_in[6];
    const float* bR   = (const float*)d_in[7];
    const float* TW   = (const float*)d_in[8];
    const float* HW   = (const float*)d_in[9];
    float* ws  = (float*)d_ws;
    float* out = (float*)d_out;

    // zero c and h[parity=0] (contiguous: first 524288 floats)
    zero_kernel<<<2048, 256, 0, stream>>>(ws, 524288);

    dim3 sgrid(16, 8, 2);
    for (int t = 0; t < TDIM; ++t) {
        lstm_step<<<sgrid, 256, 0, stream>>>(xL, xR, lenL, lenR, WL, WR, bL, bR,
                                             ws, t, t & 1);
    }

    float* ctx = ws + OFF_CTX;
    float* x1  = ws + OFF_X1;
    float* x2  = ws + OFF_X2;
    gemm_relu<<<dim3(32, 8), 256, 0, stream>>>(ctx, TW, x1, BDIM, ENC, ENC);
    gemm_relu<<<dim3(32, 8), 256, 0, stream>>>(x1, HW, x2, BDIM, ENC, ENC);
    gemm_relu<<<dim3(32, 8), 256, 0, stream>>>(x2, HW + 1024 * 1024, out, BDIM, ENC, ENC);
}

// Round 2
// 7257.477 us; speedup vs baseline: 1.8113x; 1.8113x over previous
//
#include <hip/hip_runtime.h>
#include <math.h>

// Problem constants
#define EDIM 300
#define HDIM 512
#define TDIM 100
#define BDIM 256
#define KTOT 812      // E + H
#define KP   832      // padded K (26 * 32)
#define NKS  26
#define ENC  1024

// Workspace layout (BYTE offsets)
#define B_C     0u            // c fp32 [2][256][512]            1,048,576
#define B_HHI   1048576u      // h_hi bf16 [2 par][2 d][256][512] 1,048,576
#define B_HLO   2097152u      // h_lo bf16                        1,048,576
#define B_WPHI  3145728u      // Wp_hi bf16 [2 d][2048 c'][832 k] 6,815,744
#define B_WPLO  9961472u      // Wp_lo bf16                       6,815,744
#define B_CTX   16777216u     // ctx fp32 [256][1024]             1,048,576
#define B_X1    17825792u
#define B_X2    18874368u

typedef __attribute__((ext_vector_type(8))) short bf16x8;
typedef __attribute__((ext_vector_type(4))) float f32x4;

__device__ __forceinline__ float fast_sigmoid(float x) {
    return 1.0f / (1.0f + __expf(-x));
}
__device__ __forceinline__ float fast_tanh(float x) {
    float t = __expf(2.0f * x);
    return 1.0f - 2.0f / (t + 1.0f);
}
__device__ __forceinline__ unsigned short bf16_rne(float v) {
    unsigned int u = __float_as_uint(v);
    unsigned int r = (u + 0x7fffu + ((u >> 16) & 1u)) >> 16;
    return (unsigned short)r;
}
__device__ __forceinline__ float bf16_to_f(unsigned short h) {
    return __uint_as_float(((unsigned int)h) << 16);
}
__device__ __forceinline__ void split2(float v, unsigned short& hi, unsigned short& lo) {
    hi = bf16_rne(v);
    lo = bf16_rne(v - bf16_to_f(hi));
}

__global__ void zero_kernel(float* __restrict__ p, int n) {
    int i = blockIdx.x * blockDim.x + threadIdx.x;
    if (i < n) p[i] = 0.0f;
}

// Permute + split + transpose W: Wp[d][c'][k] bf16 hi/lo, c' = (h>>4)*64 + g*16 + (h&15)
__global__ __launch_bounds__(256) void prep_w(
    const float* __restrict__ WL, const float* __restrict__ WR, char* __restrict__ ws)
{
    int bid = blockIdx.x;              // [0, 4096)
    int d   = bid >> 11;
    int cp  = bid & 2047;
    int G = cp >> 6, g = (cp >> 4) & 3, hl = cp & 15;
    int col = g * 512 + G * 16 + hl;   // original column
    const float* W = d ? WR : WL;
    unsigned short* wh = (unsigned short*)(ws + B_WPHI) + (size_t)(d * 2048 + cp) * KP;
    unsigned short* wl = (unsigned short*)(ws + B_WPLO) + (size_t)(d * 2048 + cp) * KP;
    for (int k = threadIdx.x; k < KP; k += 256) {
        float v = (k < KTOT) ? W[(size_t)k * 2048 + col] : 0.0f;
        unsigned short hi, lo;
        split2(v, hi, lo);
        wh[k] = hi;
        wl[k] = lo;
    }
}

// One LSTM timestep, both dirs, MFMA split-bf16.
// grid (16 n-tiles of 128 permuted cols, 4 m-tiles of 128 rows), 256 threads (4 waves).
// Wave tile 64x64; per k-step 48 MFMAs (4m x 4n x 3 products).
__global__ __launch_bounds__(256) void lstm_step_mfma(
    const float* __restrict__ xL, const float* __restrict__ xR,
    const int* __restrict__ lenL, const int* __restrict__ lenR,
    const float* __restrict__ bL, const float* __restrict__ bR,
    char* __restrict__ ws, int t, int par)
{
    const int by   = blockIdx.y;
    const int d    = by >> 1;
    const int brow = (by & 1) * 128;
    const int n0   = blockIdx.x * 128;

    const float* __restrict__ x    = d ? xR : xL;
    const int*   __restrict__ len  = d ? lenR : lenL;
    const float* __restrict__ bias = d ? bR : bL;

    float* __restrict__ cbuf = (float*)(ws + B_C);
    const unsigned short* __restrict__ hhi_prev = (const unsigned short*)(ws + B_HHI) + (size_t)par * 262144;
    const unsigned short* __restrict__ hlo_prev = (const unsigned short*)(ws + B_HLO) + (size_t)par * 262144;
    unsigned short* __restrict__ hhi_next = (unsigned short*)(ws + B_HHI) + (size_t)(par ^ 1) * 262144;
    unsigned short* __restrict__ hlo_next = (unsigned short*)(ws + B_HLO) + (size_t)(par ^ 1) * 262144;
    const unsigned short* __restrict__ Wph = (const unsigned short*)(ws + B_WPHI) + (size_t)d * (2048 * KP);
    const unsigned short* __restrict__ Wpl = (const unsigned short*)(ws + B_WPLO) + (size_t)d * (2048 * KP);
    float* __restrict__ ctx = (float*)(ws + B_CTX);

    __shared__ __align__(16) unsigned short As_hi[128 * 40];
    __shared__ __align__(16) unsigned short As_lo[128 * 40];
    __shared__ __align__(16) unsigned short Bs_hi[128 * 40];
    __shared__ __align__(16) unsigned short Bs_lo[128 * 40];

    const int tid = threadIdx.x;
    const int l   = tid & 63;
    const int w   = tid >> 6;
    const int wr  = w >> 1, wc = w & 1;
    const int fr  = l & 15;       // fragment row/col index
    const int fg  = l >> 4;       // k-group (0..3)

    f32x4 acc[4][4] = {};

    const int kqA = (tid & 7) * 4;        // A staging: 4 consecutive k per thread
    const int nB  = tid >> 1;             // B staging row
    const int koB = (tid & 1) * 16;

    for (int ks = 0; ks < NKS; ++ks) {
        const int k0 = ks * 32;
        // ---- stage A: 128 rows x 32 k (fp32 x / bf16-pair h sources)
        {
            const int kg = k0 + kqA;
            #pragma unroll
            for (int pass = 0; pass < 4; ++pass) {
                const int r = (tid >> 3) + pass * 32;
                const int b = brow + r;
                ushort4 vh, vl;
                if (kg < EDIM) {
                    const float4 v = *(const float4*)(x + (size_t)b * (TDIM * EDIM) + (size_t)t * EDIM + kg);
                    split2(v.x, vh.x, vl.x);
                    split2(v.y, vh.y, vl.y);
                    split2(v.z, vh.z, vl.z);
                    split2(v.w, vh.w, vl.w);
                } else if (kg < KTOT) {
                    const size_t hidx = (size_t)(d * BDIM + b) * HDIM + (kg - EDIM);
                    vh = *(const ushort4*)(hhi_prev + hidx);
                    vl = *(const ushort4*)(hlo_prev + hidx);
                } else {
                    vh = make_ushort4(0, 0, 0, 0);
                    vl = make_ushort4(0, 0, 0, 0);
                }
                *(ushort4*)&As_hi[r * 40 + kqA] = vh;
                *(ushort4*)&As_lo[r * 40 + kqA] = vl;
            }
        }
        // ---- stage B: 128 rows (c') x 32 k, pre-split bf16, contiguous 16B loads
        {
            #pragma unroll
            for (int it = 0; it < 2; ++it) {
                const int ko = koB + it * 8;
                const uint4 vh = *(const uint4*)(Wph + (size_t)(n0 + nB) * KP + k0 + ko);
                const uint4 vl = *(const uint4*)(Wpl + (size_t)(n0 + nB) * KP + k0 + ko);
                *(uint4*)&Bs_hi[nB * 40 + ko] = vh;
                *(uint4*)&Bs_lo[nB * 40 + ko] = vl;
            }
        }
        __syncthreads();
        // ---- MFMA: wave tile 64x64
        bf16x8 bh[4], bl2[4], ah[4], al[4];
        #pragma unroll
        for (int n = 0; n < 4; ++n) {
            const int row = wc * 64 + n * 16 + fr;
            bh[n]  = *(const bf16x8*)&Bs_hi[row * 40 + fg * 8];
            bl2[n] = *(const bf16x8*)&Bs_lo[row * 40 + fg * 8];
        }
        #pragma unroll
        for (int m = 0; m < 4; ++m) {
            const int row = wr * 64 + m * 16 + fr;
            ah[m] = *(const bf16x8*)&As_hi[row * 40 + fg * 8];
            al[m] = *(const bf16x8*)&As_lo[row * 40 + fg * 8];
        }
        #pragma unroll
        for (int m = 0; m < 4; ++m) {
            #pragma unroll
            for (int n = 0; n < 4; ++n) {
                acc[m][n] = __builtin_amdgcn_mfma_f32_16x16x32_bf16(ah[m], bh[n],  acc[m][n], 0, 0, 0);
                acc[m][n] = __builtin_amdgcn_mfma_f32_16x16x32_bf16(ah[m], bl2[n], acc[m][n], 0, 0, 0);
                acc[m][n] = __builtin_amdgcn_mfma_f32_16x16x32_bf16(al[m], bh[n],  acc[m][n], 0, 0, 0);
            }
        }
        __syncthreads();
    }

    // ---- epilogue: fragment n == gate (i,j,f,o); 4 gates of (row,hcol) are thread-local
    const int hcol = ((n0 + wc * 64) >> 2) + fr;
    const float bi  = bias[0 * HDIM + hcol];
    const float bj  = bias[1 * HDIM + hcol];
    const float bf_ = bias[2 * HDIM + hcol];
    const float bo  = bias[3 * HDIM + hcol];
    #pragma unroll
    for (int m = 0; m < 4; ++m) {
        #pragma unroll
        for (int r = 0; r < 4; ++r) {
            const int row = brow + wr * 64 + m * 16 + fg * 4 + r;   // batch row within dir
            const float iv = acc[m][0][r] + bi;
            const float jv = acc[m][1][r] + bj;
            const float fv = acc[m][2][r] + bf_;
            const float ov = acc[m][3][r] + bo;
            const size_t cidx = (size_t)(d * BDIM + row) * HDIM + hcol;
            const float c_new = cbuf[cidx] * fast_sigmoid(fv + 1.0f) + fast_sigmoid(iv) * fast_tanh(jv);
            const float h_new = fast_tanh(c_new) * fast_sigmoid(ov);
            cbuf[cidx] = c_new;
            unsigned short hh, hl2;
            split2(h_new, hh, hl2);
            hhi_next[cidx] = hh;
            hlo_next[cidx] = hl2;
            if (t == len[row] - 1) {
                ctx[(size_t)row * (2 * HDIM) + d * HDIM + hcol] = h_new;
            }
        }
    }
}

// C = relu(A @ W), fp32 vector path (small MLP tail). BM=32, BN=32.
__global__ __launch_bounds__(256) void gemm_relu(
    const float* __restrict__ A, const float* __restrict__ W, float* __restrict__ C,
    int M, int K, int N)
{
    __shared__ __align__(16) float As[32 * 36];
    __shared__ __align__(16) float Bs[32 * 36];
    const int tid = threadIdx.x;
    const int j   = tid & 31;
    const int mg  = tid >> 5;
    const int m0t = mg * 4;
    const int n0  = blockIdx.x * 32;
    const int b0  = blockIdx.y * 32;

    float acc[4] = {0.f, 0.f, 0.f, 0.f};
    for (int k0 = 0; k0 < K; k0 += 32) {
        #pragma unroll
        for (int pass = 0; pass < 4; ++pass) {
            int m  = mg + pass * 8;
            As[j * 36 + m] = A[(size_t)(b0 + m) * K + k0 + j];
            int kk = mg + pass * 8;
            Bs[kk * 36 + j] = W[(size_t)(k0 + kk) * N + n0 + j];
        }
        __syncthreads();
        #pragma unroll
        for (int kk = 0; kk < 32; ++kk) {
            float4 a4 = *(const float4*)&As[kk * 36 + m0t];
            float bv  = Bs[kk * 36 + j];
            acc[0] += a4.x * bv;
            acc[1] += a4.y * bv;
            acc[2] += a4.z * bv;
            acc[3] += a4.w * bv;
        }
        __syncthreads();
    }
    #pragma unroll
    for (int mi = 0; mi < 4; ++mi) {
        float v = acc[mi];
        v = v > 0.f ? v : 0.f;
        C[(size_t)(b0 + m0t + mi) * N + n0 + j] = v;
    }
}

extern "C" void kernel_launch(void* const* d_in, const int* in_sizes, int n_in,
                              void* d_out, int out_size, void* d_ws, size_t ws_size,
                              hipStream_t stream) {
    const float* xL   = (const float*)d_in[0];
    const int*   lenL = (const int*)  d_in[1];
    const float* xR   = (const float*)d_in[2];
    const int*   lenR = (const int*)  d_in[3];
    const float* WL   = (const float*)d_in[4];
    const float* bL   = (const float*)d_in[5];
    const float* WR   = (const float*)d_in[6];
    const float* bR   = (const float*)d_in[7];
    const float* TW   = (const float*)d_in[8];
    const float* HW   = (const float*)d_in[9];
    char* ws   = (char*)d_ws;
    float* out = (float*)d_out;

    // zero c + h_hi + h_lo (first 3 MB)
    zero_kernel<<<3072, 256, 0, stream>>>((float*)ws, 786432);
    // permute + split + transpose W into ws
    prep_w<<<4096, 256, 0, stream>>>(WL, WR, ws);

    dim3 sgrid(16, 4);
    for (int t = 0; t < TDIM; ++t) {
        lstm_step_mfma<<<sgrid, 256, 0, stream>>>(xL, xR, lenL, lenR, bL, bR,
                                                  ws, t, t & 1);
    }

    float* ctx = (float*)(ws + B_CTX);
    float* x1  = (float*)(ws + B_X1);
    float* x2  = (float*)(ws + B_X2);
    gemm_relu<<<dim3(32, 8), 256, 0, stream>>>(ctx, TW, x1, BDIM, ENC, ENC);
    gemm_relu<<<dim3(32, 8), 256, 0, stream>>>(x1, HW, x2, BDIM, ENC, ENC);
    gemm_relu<<<dim3(32, 8), 256, 0, stream>>>(x2, HW + 1024 * 1024, out, BDIM, ENC, ENC);
}

// Round 4
// 2368.995 us; speedup vs baseline: 5.5491x; 3.0635x over previous
//
#include <hip/hip_runtime.h>
#include <math.h>

// Problem constants
#define EDIM 300
#define HDIM 512
#define TDIM 100
#define BDIM 256
#define KTOT 812      // E + H
#define KP   832      // padded K (26 * 32)
#define KHALF 416
#define NIT  13       // k-iterations per half
#define ENC  1024

// Workspace layout (BYTE offsets)
#define B_C     0u            // c fp32 [2][256][512]                 1,048,576
#define B_HHI   1048576u      // h_hi bf16 [2 par][2 d][256][512]     1,048,576
#define B_HLO   2097152u      // h_lo bf16                            1,048,576
#define B_WPHI  3145728u      // Wp_hi bf16 [2 d][2048 c'][832 k]     6,815,744
#define B_WPLO  9961472u      // Wp_lo bf16                           6,815,744
#define B_CTX   16777216u     // ctx fp32 [256][1024]                 1,048,576
#define B_X1    17825792u
#define B_X2    18874368u
#define B_TWH   19922944u     // tail W hi bf16 [3][1024 n][1024 k]   6,291,456
#define B_TWL   26214400u
#define NEED_TAIL 32505856ull
#define B_XSHI  32505856u     // x split hi bf16 [2 d][256][100][300] 30,720,000
#define B_XSLO  63225856u
#define NEED_XS   93945856ull

// LDS byte-offset helpers (avoid pointer-array static initializers)
#define L_AS_HI(hf) ((hf) * 5120)
#define L_AS_LO(hf) (10240 + (hf) * 5120)
#define L_BS_HI(hf) (20480 + (hf) * 5120)
#define L_BS_LO(hf) (30720 + (hf) * 5120)

typedef __attribute__((ext_vector_type(8))) short bf16x8;
typedef __attribute__((ext_vector_type(4))) float f32x4;

__device__ __forceinline__ float fast_sigmoid(float x) {
    return 1.0f / (1.0f + __expf(-x));
}
__device__ __forceinline__ float fast_tanh(float x) {
    float t = __expf(2.0f * x);
    return 1.0f - 2.0f / (t + 1.0f);
}
__device__ __forceinline__ unsigned short bf16_rne(float v) {
    unsigned int u = __float_as_uint(v);
    unsigned int r = (u + 0x7fffu + ((u >> 16) & 1u)) >> 16;
    return (unsigned short)r;
}
__device__ __forceinline__ float bf16_to_f(unsigned short h) {
    return __uint_as_float(((unsigned int)h) << 16);
}
__device__ __forceinline__ void split2(float v, unsigned short& hi, unsigned short& lo) {
    hi = bf16_rne(v);
    lo = bf16_rne(v - bf16_to_f(hi));
}

__global__ void zero_kernel(float* __restrict__ p, int n) {
    int i = blockIdx.x * blockDim.x + threadIdx.x;
    if (i < n) p[i] = 0.0f;
}

// ---- prep: permute + split + transpose lstm W via LDS tiles.
// grid = 2 d * 13 ktiles * 32 ctiles = 832 blocks, 256 thr.
__global__ __launch_bounds__(256) void prep_w_lstm(
    const float* __restrict__ WL, const float* __restrict__ WR, char* __restrict__ ws)
{
    __shared__ float tile[64 * 65];
    int bid = blockIdx.x;
    int d = bid / (13 * 32);
    int rem = bid - d * (13 * 32);
    int kt = rem >> 5;                // 0..12
    int ct = rem & 31;                // 0..31
    const int k0 = kt * 64;
    const float* W = d ? WR : WL;
    for (int pass = 0; pass < 16; ++pass) {
        int idx = pass * 256 + threadIdx.x;
        int kk = idx >> 6, c = idx & 63;
        int g = c >> 4, hl = c & 15;
        int col = g * HDIM + ct * 16 + hl;
        int kg = k0 + kk;
        tile[kk * 65 + c] = (kg < KTOT) ? W[(size_t)kg * 2048 + col] : 0.0f;
    }
    __syncthreads();
    unsigned short* wh = (unsigned short*)(ws + B_WPHI) + (size_t)d * 2048 * KP;
    unsigned short* wl = (unsigned short*)(ws + B_WPLO) + (size_t)d * 2048 * KP;
    for (int pass = 0; pass < 16; ++pass) {
        int idx = pass * 256 + threadIdx.x;
        int c = idx >> 6, kk = idx & 63;
        unsigned short hi, lo;
        split2(tile[kk * 65 + c], hi, lo);
        size_t o = (size_t)(ct * 64 + c) * KP + k0 + kk;
        wh[o] = hi;
        wl[o] = lo;
    }
}

// ---- prep: transpose + split tail weights. layer l: 0=TW, 1=HW[0], 2=HW[1].
// grid = 3 * 16 kt * 16 ct = 768 blocks.
__global__ __launch_bounds__(256) void prep_w_tail(
    const float* __restrict__ TW, const float* __restrict__ HW, char* __restrict__ ws)
{
    __shared__ float tile[64 * 65];
    int bid = blockIdx.x;
    int l = bid / 256;
    int rem = bid - l * 256;
    int kt = rem >> 4, ct = rem & 15;
    const int k0 = kt * 64, n0 = ct * 64;
    const float* W = (l == 0) ? TW : (HW + (size_t)(l - 1) * ENC * ENC);
    for (int pass = 0; pass < 16; ++pass) {
        int idx = pass * 256 + threadIdx.x;
        int kk = idx >> 6, c = idx & 63;
        tile[kk * 65 + c] = W[(size_t)(k0 + kk) * ENC + n0 + c];
    }
    __syncthreads();
    unsigned short* wh = (unsigned short*)(ws + B_TWH) + (size_t)l * ENC * ENC;
    unsigned short* wl = (unsigned short*)(ws + B_TWL) + (size_t)l * ENC * ENC;
    for (int pass = 0; pass < 16; ++pass) {
        int idx = pass * 256 + threadIdx.x;
        int c = idx >> 6, kk = idx & 63;
        unsigned short hi, lo;
        split2(tile[kk * 65 + c], hi, lo);
        size_t o = (size_t)(n0 + c) * ENC + k0 + kk;
        wh[o] = hi;
        wl[o] = lo;
    }
}

// ---- prep: split x fp32 -> bf16 hi/lo, flat copy.
__global__ __launch_bounds__(256) void prep_x(
    const float* __restrict__ xL, const float* __restrict__ xR, char* __restrict__ ws)
{
    const long long NQ = 2LL * BDIM * TDIM * EDIM / 4;   // 3,840,000
    const long long N1 = (long long)BDIM * TDIM * EDIM;  // per-dir floats
    unsigned short* xh = (unsigned short*)(ws + B_XSHI);
    unsigned short* xl = (unsigned short*)(ws + B_XSLO);
    for (long long qi = blockIdx.x * blockDim.x + threadIdx.x; qi < NQ;
         qi += (long long)gridDim.x * blockDim.x) {
        long long i = qi * 4;
        const float* src = (i < N1) ? (xL + i) : (xR + (i - N1));
        float4 v = *(const float4*)src;
        ushort4 vh, vl;
        split2(v.x, vh.x, vl.x);
        split2(v.y, vh.y, vl.y);
        split2(v.z, vh.z, vl.z);
        split2(v.w, vh.w, vl.w);
        *(ushort4*)(xh + i) = vh;
        *(ushort4*)(xl + i) = vl;
    }
}

// ---- One LSTM timestep. grid 256 blocks x 512 thr (8 waves).
// Block tile 64m x 64n; waves: kh = K-half (2) x ms = m-subtile (4); wave tile 16m x 64n.
// bid decode keeps the 8 m-blocks sharing a W n-slab on one XCD (bid & 7).
template<bool USE_XS>
__global__ __launch_bounds__(512, 2) void lstm_step_mfma2(
    const float* __restrict__ xL, const float* __restrict__ xR,
    const int* __restrict__ lenL, const int* __restrict__ lenR,
    const float* __restrict__ bL, const float* __restrict__ bR,
    char* __restrict__ ws, int t, int par)
{
    const int bid  = blockIdx.x;
    const int xcd  = bid & 7;
    const int rest = bid >> 3;
    const int ntile = xcd * 4 + (rest & 3);   // 0..31
    const int mt    = rest >> 2;              // 0..7
    const int n0    = ntile * 64;
    const int d     = mt >> 2;
    const int brow  = (mt & 3) * 64;

    const int* __restrict__ len   = d ? lenR : lenL;
    const float* __restrict__ bias = d ? bR : bL;
    const float* __restrict__ x    = d ? xR : xL;

    float* __restrict__ cbuf = (float*)(ws + B_C);
    const unsigned short* __restrict__ hhi_prev = (const unsigned short*)(ws + B_HHI) + (size_t)par * 262144;
    const unsigned short* __restrict__ hlo_prev = (const unsigned short*)(ws + B_HLO) + (size_t)par * 262144;
    unsigned short* __restrict__ hhi_next = (unsigned short*)(ws + B_HHI) + (size_t)(par ^ 1) * 262144;
    unsigned short* __restrict__ hlo_next = (unsigned short*)(ws + B_HLO) + (size_t)(par ^ 1) * 262144;
    const unsigned short* __restrict__ Wph = (const unsigned short*)(ws + B_WPHI) + (size_t)d * 2048 * KP;
    const unsigned short* __restrict__ Wpl = (const unsigned short*)(ws + B_WPLO) + (size_t)d * 2048 * KP;
    const unsigned short* __restrict__ xsh = (const unsigned short*)(ws + B_XSHI);
    const unsigned short* __restrict__ xsl = (const unsigned short*)(ws + B_XSLO);
    float* __restrict__ ctx = (float*)(ws + B_CTX);

    // LDS: 8 staging buffers of 64x40 ushorts (5120 B each) = 40960 B; reduce overlays.
    __shared__ __align__(16) char smem[40960];

    const int tid  = threadIdx.x;
    const int l    = tid & 63;
    const int w    = tid >> 6;
    const int kh   = w >> 2;                   // K-half
    const int ms   = w & 3;                    // m-subtile
    const int fr   = l & 15;
    const int fg   = l >> 4;

    const int arow = tid >> 3;                 // 0..63 (staging row/col)
    const int q    = (tid & 7) * 4;            // 0..28 (k-quad)

    f32x4 acc[4] = {};                         // per n-fragment (= gate)

    for (int it = 0; it < NIT; ++it) {
        // ---- stage A (both halves) + B (both halves)
        #pragma unroll
        for (int hf = 0; hf < 2; ++hf) {
            const int kg = hf * KHALF + it * 32 + q;
            ushort4 vh, vl;
            if (kg < EDIM) {
                if (USE_XS) {
                    const size_t xo = ((size_t)(d * BDIM + brow + arow) * TDIM + t) * EDIM + kg;
                    vh = *(const ushort4*)(xsh + xo);
                    vl = *(const ushort4*)(xsl + xo);
                } else {
                    const float4 v = *(const float4*)(x + (size_t)(brow + arow) * (TDIM * EDIM) + (size_t)t * EDIM + kg);
                    split2(v.x, vh.x, vl.x);
                    split2(v.y, vh.y, vl.y);
                    split2(v.z, vh.z, vl.z);
                    split2(v.w, vh.w, vl.w);
                }
            } else if (kg < KTOT) {
                const size_t hidx = (size_t)(d * BDIM + brow + arow) * HDIM + (kg - EDIM);
                vh = *(const ushort4*)(hhi_prev + hidx);
                vl = *(const ushort4*)(hlo_prev + hidx);
            } else {
                vh = make_ushort4(0, 0, 0, 0);
                vl = make_ushort4(0, 0, 0, 0);
            }
            *(ushort4*)(smem + L_AS_HI(hf) + (arow * 40 + q) * 2) = vh;
            *(ushort4*)(smem + L_AS_LO(hf) + (arow * 40 + q) * 2) = vl;
            // B: W slab (pre-split, pre-transposed, zero-padded to KP)
            const size_t wo = (size_t)(n0 + arow) * KP + kg;
            *(ushort4*)(smem + L_BS_HI(hf) + (arow * 40 + q) * 2) = *(const ushort4*)(Wph + wo);
            *(ushort4*)(smem + L_BS_LO(hf) + (arow * 40 + q) * 2) = *(const ushort4*)(Wpl + wo);
        }
        __syncthreads();
        // ---- compute: wave (kh, ms) consumes half kh
        const int aoff = ((ms * 16 + fr) * 40 + fg * 8) * 2;
        const bf16x8 ah = *(const bf16x8*)(smem + L_AS_HI(kh) + aoff);
        const bf16x8 al = *(const bf16x8*)(smem + L_AS_LO(kh) + aoff);
        #pragma unroll
        for (int nf = 0; nf < 4; ++nf) {
            const int boff = ((nf * 16 + fr) * 40 + fg * 8) * 2;
            const bf16x8 bh = *(const bf16x8*)(smem + L_BS_HI(kh) + boff);
            const bf16x8 bl = *(const bf16x8*)(smem + L_BS_LO(kh) + boff);
            acc[nf] = __builtin_amdgcn_mfma_f32_16x16x32_bf16(ah, bh, acc[nf], 0, 0, 0);
            acc[nf] = __builtin_amdgcn_mfma_f32_16x16x32_bf16(ah, bl, acc[nf], 0, 0, 0);
            acc[nf] = __builtin_amdgcn_mfma_f32_16x16x32_bf16(al, bh, acc[nf], 0, 0, 0);
        }
        __syncthreads();
    }

    // ---- cross-half reduce via LDS (overlay on smem)
    float* red = (float*)smem;                 // 64 x 65 floats = 16640 B
    if (kh == 1) {
        #pragma unroll
        for (int nf = 0; nf < 4; ++nf)
            #pragma unroll
            for (int r = 0; r < 4; ++r)
                red[(ms * 16 + fg * 4 + r) * 65 + nf * 16 + fr] = acc[nf][r];
    }
    __syncthreads();
    if (kh == 0) {
        #pragma unroll
        for (int nf = 0; nf < 4; ++nf)
            #pragma unroll
            for (int r = 0; r < 4; ++r)
                acc[nf][r] += red[(ms * 16 + fg * 4 + r) * 65 + nf * 16 + fr];

        // ---- epilogue: nf == gate, hcol = ntile*16 + fr
        const int hcol = ntile * 16 + fr;
        const float bi  = bias[0 * HDIM + hcol];
        const float bj  = bias[1 * HDIM + hcol];
        const float bf_ = bias[2 * HDIM + hcol];
        const float bo  = bias[3 * HDIM + hcol];
        #pragma unroll
        for (int r = 0; r < 4; ++r) {
            const int row = brow + ms * 16 + fg * 4 + r;
            const float iv = acc[0][r] + bi;
            const float jv = acc[1][r] + bj;
            const float fv = acc[2][r] + bf_;
            const float ov = acc[3][r] + bo;
            const size_t cidx = (size_t)(d * BDIM + row) * HDIM + hcol;
            const float c_new = cbuf[cidx] * fast_sigmoid(fv + 1.0f) + fast_sigmoid(iv) * fast_tanh(jv);
            const float h_new = fast_tanh(c_new) * fast_sigmoid(ov);
            cbuf[cidx] = c_new;
            unsigned short hh, hl2;
            split2(h_new, hh, hl2);
            hhi_next[cidx] = hh;
            hlo_next[cidx] = hl2;
            if (t == len[row] - 1) {
                ctx[(size_t)row * (2 * HDIM) + d * HDIM + hcol] = h_new;
            }
        }
    }
}

// ---- tail GEMM: C = relu(A @ W), A [256,1024] fp32, W pre-split [1024 n][1024 k].
// grid 64 blocks (4 mt x 16 nt) x 512 thr, same 8-wave K-split structure.
__global__ __launch_bounds__(512, 2) void gemm_relu_mfma(
    const float* __restrict__ A, const unsigned short* __restrict__ Wh,
    const unsigned short* __restrict__ Wl, float* __restrict__ C)
{
    const int ntile = blockIdx.x & 15;
    const int mt    = blockIdx.x >> 4;
    const int n0    = ntile * 64;
    const int m0    = mt * 64;

    __shared__ __align__(16) char smem[40960];

    const int tid  = threadIdx.x;
    const int l    = tid & 63;
    const int w    = tid >> 6;
    const int kh   = w >> 2;
    const int ms   = w & 3;
    const int fr   = l & 15;
    const int fg   = l >> 4;
    const int arow = tid >> 3;
    const int q    = (tid & 7) * 4;

    f32x4 acc[4] = {};

    for (int it = 0; it < 16; ++it) {
        #pragma unroll
        for (int hf = 0; hf < 2; ++hf) {
            const int kg = hf * 512 + it * 32 + q;
            const float4 v = *(const float4*)(A + (size_t)(m0 + arow) * ENC + kg);
            ushort4 vh, vl;
            split2(v.x, vh.x, vl.x);
            split2(v.y, vh.y, vl.y);
            split2(v.z, vh.z, vl.z);
            split2(v.w, vh.w, vl.w);
            *(ushort4*)(smem + L_AS_HI(hf) + (arow * 40 + q) * 2) = vh;
            *(ushort4*)(smem + L_AS_LO(hf) + (arow * 40 + q) * 2) = vl;
            const size_t wo = (size_t)(n0 + arow) * ENC + kg;
            *(ushort4*)(smem + L_BS_HI(hf) + (arow * 40 + q) * 2) = *(const ushort4*)(Wh + wo);
            *(ushort4*)(smem + L_BS_LO(hf) + (arow * 40 + q) * 2) = *(const ushort4*)(Wl + wo);
        }
        __syncthreads();
        const int aoff = ((ms * 16 + fr) * 40 + fg * 8) * 2;
        const bf16x8 ah = *(const bf16x8*)(smem + L_AS_HI(kh) + aoff);
        const bf16x8 al = *(const bf16x8*)(smem + L_AS_LO(kh) + aoff);
        #pragma unroll
        for (int nf = 0; nf < 4; ++nf) {
            const int boff = ((nf * 16 + fr) * 40 + fg * 8) * 2;
            const bf16x8 bh = *(const bf16x8*)(smem + L_BS_HI(kh) + boff);
            const bf16x8 bl = *(const bf16x8*)(smem + L_BS_LO(kh) + boff);
            acc[nf] = __builtin_amdgcn_mfma_f32_16x16x32_bf16(ah, bh, acc[nf], 0, 0, 0);
            acc[nf] = __builtin_amdgcn_mfma_f32_16x16x32_bf16(ah, bl, acc[nf], 0, 0, 0);
            acc[nf] = __builtin_amdgcn_mfma_f32_16x16x32_bf16(al, bh, acc[nf], 0, 0, 0);
        }
        __syncthreads();
    }

    float* red = (float*)smem;
    if (kh == 1) {
        #pragma unroll
        for (int nf = 0; nf < 4; ++nf)
            #pragma unroll
            for (int r = 0; r < 4; ++r)
                red[(ms * 16 + fg * 4 + r) * 65 + nf * 16 + fr] = acc[nf][r];
    }
    __syncthreads();
    if (kh == 0) {
        #pragma unroll
        for (int nf = 0; nf < 4; ++nf) {
            #pragma unroll
            for (int r = 0; r < 4; ++r) {
                float v = acc[nf][r] + red[(ms * 16 + fg * 4 + r) * 65 + nf * 16 + fr];
                v = v > 0.f ? v : 0.f;
                const int row = m0 + ms * 16 + fg * 4 + r;
                C[(size_t)row * ENC + n0 + nf * 16 + fr] = v;
            }
        }
    }
}

// fp32 fallback tail GEMM (used only if ws too small for split weights)
__global__ __launch_bounds__(256) void gemm_relu(
    const float* __restrict__ A, const float* __restrict__ W, float* __restrict__ C,
    int M, int K, int N)
{
    __shared__ __align__(16) float As[32 * 36];
    __shared__ __align__(16) float Bs[32 * 36];
    const int tid = threadIdx.x;
    const int j   = tid & 31;
    const int mg  = tid >> 5;
    const int m0t = mg * 4;
    const int n0  = blockIdx.x * 32;
    const int b0  = blockIdx.y * 32;

    float acc[4] = {0.f, 0.f, 0.f, 0.f};
    for (int k0 = 0; k0 < K; k0 += 32) {
        #pragma unroll
        for (int pass = 0; pass < 4; ++pass) {
            int m  = mg + pass * 8;
            As[j * 36 + m] = A[(size_t)(b0 + m) * K + k0 + j];
            int kk = mg + pass * 8;
            Bs[kk * 36 + j] = W[(size_t)(k0 + kk) * N + n0 + j];
        }
        __syncthreads();
        #pragma unroll
        for (int kk = 0; kk < 32; ++kk) {
            float4 a4 = *(const float4*)&As[kk * 36 + m0t];
            float bv  = Bs[kk * 36 + j];
            acc[0] += a4.x * bv;
            acc[1] += a4.y * bv;
            acc[2] += a4.z * bv;
            acc[3] += a4.w * bv;
        }
        __syncthreads();
    }
    #pragma unroll
    for (int mi = 0; mi < 4; ++mi) {
        float v = acc[mi];
        v = v > 0.f ? v : 0.f;
        C[(size_t)(b0 + m0t + mi) * N + n0 + j] = v;
    }
}

extern "C" void kernel_launch(void* const* d_in, const int* in_sizes, int n_in,
                              void* d_out, int out_size, void* d_ws, size_t ws_size,
                              hipStream_t stream) {
    const float* xL   = (const float*)d_in[0];
    const int*   lenL = (const int*)  d_in[1];
    const float* xR   = (const float*)d_in[2];
    const int*   lenR = (const int*)  d_in[3];
    const float* WL   = (const float*)d_in[4];
    const float* bL   = (const float*)d_in[5];
    const float* WR   = (const float*)d_in[6];
    const float* bR   = (const float*)d_in[7];
    const float* TW   = (const float*)d_in[8];
    const float* HW   = (const float*)d_in[9];
    char* ws   = (char*)d_ws;
    float* out = (float*)d_out;

    const bool use_tail = ws_size >= NEED_TAIL;
    const bool use_xs   = ws_size >= NEED_XS;

    // zero c + h (both parities, hi+lo): first 3 MB
    zero_kernel<<<3072, 256, 0, stream>>>((float*)ws, 786432);
    prep_w_lstm<<<832, 256, 0, stream>>>(WL, WR, ws);
    if (use_tail) prep_w_tail<<<768, 256, 0, stream>>>(TW, HW, ws);
    if (use_xs)   prep_x<<<2048, 256, 0, stream>>>(xL, xR, ws);

    for (int t = 0; t < TDIM; ++t) {
        if (use_xs)
            lstm_step_mfma2<true><<<256, 512, 0, stream>>>(xL, xR, lenL, lenR, bL, bR, ws, t, t & 1);
        else
            lstm_step_mfma2<false><<<256, 512, 0, stream>>>(xL, xR, lenL, lenR, bL, bR, ws, t, t & 1);
    }

    float* ctx = (float*)(ws + B_CTX);
    float* x1  = (float*)(ws + B_X1);
    float* x2  = (float*)(ws + B_X2);
    if (use_tail) {
        const unsigned short* twh = (const unsigned short*)(ws + B_TWH);
        const unsigned short* twl = (const unsigned short*)(ws + B_TWL);
        gemm_relu_mfma<<<64, 512, 0, stream>>>(ctx, twh,                twl,                x1);
        gemm_relu_mfma<<<64, 512, 0, stream>>>(x1,  twh + 1024 * 1024, twl + 1024 * 1024,  x2);
        gemm_relu_mfma<<<64, 512, 0, stream>>>(x2,  twh + 2048 * 1024, twl + 2048 * 1024,  out);
    } else {
        gemm_relu<<<dim3(32, 8), 256, 0, stream>>>(ctx, TW, x1, BDIM, ENC, ENC);
        gemm_relu<<<dim3(32, 8), 256, 0, stream>>>(x1, HW, x2, BDIM, ENC, ENC);
        gemm_relu<<<dim3(32, 8), 256, 0, stream>>>(x2, HW + 1024 * 1024, out, BDIM, ENC, ENC);
    }
}